// Round 1
// baseline (665.498 us; speedup 1.0000x reference)
//
#include <hip/hip_runtime.h>
#include <cstddef>

#define L_SEQ 4096
#define EMB   1024
#define NH    16
#define HD    64
#define N3    3072
#define CHUNK 64
#define NCHUNK 64
#define EPS 1e-6f

// ---------------------------------------------------------------------------
// K1/K5: classic fp32 SGEMM, 128x128 block tile, BK=8, 256 threads, 8x8/thread
// MODE 0: qkv = x @ qkv_w + b, fused elu+1 on q/k, scatter to head-major Q',K',V
// MODE 1: out = attn @ out_w + b, row-major to d_out
// ---------------------------------------------------------------------------
template<int MODE>
__global__ __launch_bounds__(256)
void sgemm128(const float* __restrict__ A, const float* __restrict__ Bw,
              const float* __restrict__ bias,
              float* __restrict__ o0, float* __restrict__ o1, float* __restrict__ o2,
              int N)
{
    __shared__ float As[8][128];   // [k][m] (transposed on store)
    __shared__ float Bs[8][128];   // [k][n]
    const int tid = threadIdx.x;
    const int bx = blockIdx.x;     // n tile
    const int by = blockIdx.y;     // m tile
    const int tx = tid & 15;
    const int ty = tid >> 4;
    const int arow = tid >> 1;          // 0..127
    const int acol = (tid & 1) << 2;    // 0 or 4
    const int brow = tid >> 5;          // 0..7
    const int bcol = (tid & 31) << 2;   // 0..124
    const float* Aptr = A + (size_t)(by * 128 + arow) * 1024 + acol;
    const float* Bptr = Bw + (size_t)brow * N + bx * 128 + bcol;

    float acc[8][8];
#pragma unroll
    for (int i = 0; i < 8; ++i)
#pragma unroll
        for (int j = 0; j < 8; ++j) acc[i][j] = 0.f;

    for (int k0 = 0; k0 < 1024; k0 += 8) {
        const float4 av = *(const float4*)(Aptr + k0);
        const float4 bv = *(const float4*)(Bptr + (size_t)k0 * N);
        __syncthreads();
        As[acol + 0][arow] = av.x;
        As[acol + 1][arow] = av.y;
        As[acol + 2][arow] = av.z;
        As[acol + 3][arow] = av.w;
        *(float4*)&Bs[brow][bcol] = bv;
        __syncthreads();
#pragma unroll
        for (int kk = 0; kk < 8; ++kk) {
            float ar[8], br[8];
            *(float4*)&ar[0] = *(const float4*)&As[kk][ty * 8];
            *(float4*)&ar[4] = *(const float4*)&As[kk][ty * 8 + 4];
            *(float4*)&br[0] = *(const float4*)&Bs[kk][tx * 8];
            *(float4*)&br[4] = *(const float4*)&Bs[kk][tx * 8 + 4];
#pragma unroll
            for (int i = 0; i < 8; ++i)
#pragma unroll
                for (int j = 0; j < 8; ++j)
                    acc[i][j] += ar[i] * br[j];
        }
    }

    const int n0 = bx * 128 + tx * 8;
#pragma unroll
    for (int i = 0; i < 8; ++i) {
        const int m = by * 128 + ty * 8 + i;
        float vals[8];
#pragma unroll
        for (int j = 0; j < 8; ++j) vals[j] = acc[i][j] + bias[n0 + j];
        if (MODE == 0) {
            const int r  = n0 >> 10;       // 0=q 1=k 2=v (uniform per block)
            const int nn = n0 & 1023;
            const int h  = nn >> 6;
            const int d0 = nn & 63;        // 8-aligned -> 8 consecutive d, one head
            float* base = (r == 0) ? o0 : (r == 1 ? o1 : o2);
            if (r < 2) {
#pragma unroll
                for (int j = 0; j < 8; ++j) {
                    const float v = vals[j];
                    vals[j] = (v > 0.f) ? (v + 1.f) : expf(v);  // elu(v)+1
                }
            }
            float* dst = base + ((size_t)(h * L_SEQ + m)) * HD + d0;
            *(float4*)dst       = make_float4(vals[0], vals[1], vals[2], vals[3]);
            *(float4*)(dst + 4) = make_float4(vals[4], vals[5], vals[6], vals[7]);
        } else {
            float* dst = o0 + (size_t)m * N + n0;
            *(float4*)dst       = make_float4(vals[0], vals[1], vals[2], vals[3]);
            *(float4*)(dst + 4) = make_float4(vals[4], vals[5], vals[6], vals[7]);
        }
    }
}

// ---------------------------------------------------------------------------
// K2: per-(head,chunk) state sums  S_c[d][e] = sum_l k'[l][d] v[l][e],
//                                  z_c[d]    = sum_l k'[l][d]
// ---------------------------------------------------------------------------
__global__ __launch_bounds__(256)
void chunk_state(const float* __restrict__ Kp, const float* __restrict__ V,
                 float* __restrict__ Sc, float* __restrict__ zc)
{
    __shared__ float Kc[CHUNK * HD];
    __shared__ float Vc[CHUNK * HD];
    const int c = blockIdx.x, h = blockIdx.y;
    const int tid = threadIdx.x;
    const float4* Kg = (const float4*)(Kp + ((size_t)h * L_SEQ + c * CHUNK) * HD);
    const float4* Vg = (const float4*)(V  + ((size_t)h * L_SEQ + c * CHUNK) * HD);
    float4* K4 = (float4*)Kc;
    float4* V4 = (float4*)Vc;
#pragma unroll
    for (int i = 0; i < 4; ++i) {       // 1024 float4 total / 256 threads
        K4[i * 256 + tid] = Kg[i * 256 + tid];
        V4[i * 256 + tid] = Vg[i * 256 + tid];
    }
    __syncthreads();
    const int d0 = (tid >> 4) << 2;
    const int e0 = (tid & 15) << 2;
    float acc[4][4] = {{0.f}};
    for (int l = 0; l < CHUNK; ++l) {
        const float4 kd = *(const float4*)&Kc[l * HD + d0];
        const float4 ve = *(const float4*)&Vc[l * HD + e0];
        const float k_[4] = {kd.x, kd.y, kd.z, kd.w};
        const float v_[4] = {ve.x, ve.y, ve.z, ve.w};
#pragma unroll
        for (int i = 0; i < 4; ++i)
#pragma unroll
            for (int j = 0; j < 4; ++j)
                acc[i][j] += k_[i] * v_[j];
    }
    float* Sout = Sc + ((size_t)(h * NCHUNK + c)) * HD * HD;
#pragma unroll
    for (int i = 0; i < 4; ++i)
        *(float4*)&Sout[(d0 + i) * HD + e0] =
            make_float4(acc[i][0], acc[i][1], acc[i][2], acc[i][3]);
    if (tid < HD) {
        float z = 0.f;
        for (int l = 0; l < CHUNK; ++l) z += Kc[l * HD + tid];
        zc[((size_t)(h * NCHUNK + c)) * HD + tid] = z;
    }
}

// ---------------------------------------------------------------------------
// K3: exclusive prefix over chunks (per head): S0[c] = sum_{c'<c} Sc[c'],
//     z0 likewise. One thread per (h, d, e) entry.
// ---------------------------------------------------------------------------
__global__ __launch_bounds__(256)
void prefix_scan(const float* __restrict__ Sc, float* __restrict__ S0,
                 const float* __restrict__ zc, float* __restrict__ z0)
{
    const int g = blockIdx.x * 256 + threadIdx.x;   // 0 .. NH*4096-1
    const int h  = g >> 12;
    const int de = g & 4095;
    float run = 0.f;
    for (int c = 0; c < NCHUNK; ++c) {
        const size_t idx = ((size_t)(h * NCHUNK + c)) * 4096 + de;
        S0[idx] = run;
        run += Sc[idx];
    }
    if (g < NH * HD) {
        const int h2 = g >> 6, d = g & 63;
        float rz = 0.f;
        for (int c = 0; c < NCHUNK; ++c) {
            const size_t idx = ((size_t)(h2 * NCHUNK + c)) * HD + d;
            z0[idx] = rz;
            rz += zc[idx];
        }
    }
}

// ---------------------------------------------------------------------------
// K4: per-(head,chunk) output.
//   A[i][j] = q'_i . k'_j  (masked j<=i);  O = A@V + Q'@S0;
//   norm_i = rowsum(A) + q'_i . z0;  attn[l][h*64+e] = O/(norm+eps)
// LDS strides padded (68 / 65) to break power-of-2 bank aliasing.
// ---------------------------------------------------------------------------
#define QS 68   // padded row stride for Qc/Kc/Vc
#define AS 65   // padded row stride for As

__global__ __launch_bounds__(256)
void chunk_output(const float* __restrict__ Qp, const float* __restrict__ Kp,
                  const float* __restrict__ V,  const float* __restrict__ S0,
                  const float* __restrict__ z0, float* __restrict__ attn)
{
    __shared__ float Qc[CHUNK * QS];
    __shared__ float Kc[CHUNK * QS];
    __shared__ float Vc[CHUNK * QS];
    __shared__ float Asm[32 * AS];
    __shared__ float npart[256];
    __shared__ float normL[32];
    __shared__ float z0s[HD];
    const int c = blockIdx.x, h = blockIdx.y;
    const int tid = threadIdx.x;
    const size_t rowbase = ((size_t)h * L_SEQ + c * CHUNK) * HD;
    const float4* Qg = (const float4*)(Qp + rowbase);
    const float4* Kg = (const float4*)(Kp + rowbase);
    const float4* Vg = (const float4*)(V  + rowbase);
#pragma unroll
    for (int f = tid; f < 1024; f += 256) {     // 64 rows * 16 float4
        const int l = f >> 4, c4 = (f & 15) << 2;
        *(float4*)&Qc[l * QS + c4] = Qg[f];
        *(float4*)&Kc[l * QS + c4] = Kg[f];
        *(float4*)&Vc[l * QS + c4] = Vg[f];
    }
    if (tid < HD) z0s[tid] = z0[((size_t)(h * NCHUNK + c)) * HD + tid];
    __syncthreads();
    const float* S0g = S0 + ((size_t)(h * NCHUNK + c)) * 4096;

    for (int it = 0; it < 2; ++it) {
        // ---- stage a: score tile A (32 rows x 64 cols), masked ----
        {
            const int ii = tid >> 3;          // 0..31
            const int jg = tid & 7;           // 8 j's each
            const int i  = it * 32 + ii;
            float a[8] = {0.f, 0.f, 0.f, 0.f, 0.f, 0.f, 0.f, 0.f};
            for (int dq = 0; dq < 16; ++dq) {
                const float4 q4 = *(const float4*)&Qc[i * QS + dq * 4];
#pragma unroll
                for (int jj = 0; jj < 8; ++jj) {
                    const int j = jg * 8 + jj;
                    const float4 k4 = *(const float4*)&Kc[j * QS + dq * 4];
                    a[jj] += q4.x * k4.x + q4.y * k4.y + q4.z * k4.z + q4.w * k4.w;
                }
            }
            float np = 0.f;
#pragma unroll
            for (int jj = 0; jj < 8; ++jj) {
                const int j = jg * 8 + jj;
                const float v = (j <= i) ? a[jj] : 0.f;
                Asm[ii * AS + j] = v;
                np += v;
            }
            npart[tid] = np;
        }
        __syncthreads();
        if (tid < 32) {
            const int i = it * 32 + tid;
            float s = 0.f;
#pragma unroll
            for (int g = 0; g < 8; ++g) s += npart[tid * 8 + g];
            for (int d = 0; d < HD; ++d) s += Qc[i * QS + d] * z0s[d];
            normL[tid] = s;
        }
        __syncthreads();
        // ---- stage b: O = A@V + Q'@S0, normalize, store ----
        {
            const int ii = tid >> 3;              // 0..31 (row)
            const int e0 = (tid & 7) * 8;         // 8 consecutive e -> coalesced
            const int i  = it * 32 + ii;
            float o[8] = {0.f, 0.f, 0.f, 0.f, 0.f, 0.f, 0.f, 0.f};
            for (int d = 0; d < HD; ++d) {
                const float qv = Qc[i * QS + d];
                const float4 sa = *(const float4*)&S0g[d * HD + e0];
                const float4 sb = *(const float4*)&S0g[d * HD + e0 + 4];
                o[0] += qv * sa.x; o[1] += qv * sa.y; o[2] += qv * sa.z; o[3] += qv * sa.w;
                o[4] += qv * sb.x; o[5] += qv * sb.y; o[6] += qv * sb.z; o[7] += qv * sb.w;
            }
            for (int j = 0; j < CHUNK; ++j) {
                const float av = Asm[ii * AS + j];
                const float4 va = *(const float4*)&Vc[j * QS + e0];
                const float4 vb = *(const float4*)&Vc[j * QS + e0 + 4];
                o[0] += av * va.x; o[1] += av * va.y; o[2] += av * va.z; o[3] += av * va.w;
                o[4] += av * vb.x; o[5] += av * vb.y; o[6] += av * vb.z; o[7] += av * vb.w;
            }
            const float nv = normL[ii] + EPS;
            float* dst = attn + ((size_t)(c * CHUNK + i)) * EMB + h * HD + e0;
            *(float4*)dst       = make_float4(o[0] / nv, o[1] / nv, o[2] / nv, o[3] / nv);
            *(float4*)(dst + 4) = make_float4(o[4] / nv, o[5] / nv, o[6] / nv, o[7] / nv);
        }
        __syncthreads();
    }
}

// ---------------------------------------------------------------------------
extern "C" void kernel_launch(void* const* d_in, const int* in_sizes, int n_in,
                              void* d_out, int out_size, void* d_ws, size_t ws_size,
                              hipStream_t stream)
{
    const float* x     = (const float*)d_in[0];
    const float* qkv_w = (const float*)d_in[1];
    const float* qkv_b = (const float*)d_in[2];
    const float* out_w = (const float*)d_in[3];
    const float* out_b = (const float*)d_in[4];
    float* out = (float*)d_out;

    float* ws   = (float*)d_ws;
    float* Qp   = ws;                    // H*L*D = 4194304
    float* Kp   = Qp + 4194304;
    float* Vv   = Kp + 4194304;
    float* Sc   = Vv + 4194304;          // H*NC*D*D = 4194304
    float* S0   = Sc + 4194304;
    float* zc   = S0 + 4194304;          // H*NC*D = 65536
    float* z0   = zc + 65536;
    float* attn = z0 + 65536;            // L*E = 4194304

    // K1: qkv GEMM + bias + elu+1 + head-major scatter
    sgemm128<0><<<dim3(N3 / 128, L_SEQ / 128), 256, 0, stream>>>(
        x, qkv_w, qkv_b, Qp, Kp, Vv, N3);
    // K2: per-chunk state sums
    chunk_state<<<dim3(NCHUNK, NH), 256, 0, stream>>>(Kp, Vv, Sc, zc);
    // K3: exclusive prefix over chunks
    prefix_scan<<<dim3((NH * 4096) / 256), 256, 0, stream>>>(Sc, S0, zc, z0);
    // K4: intra-chunk attention output
    chunk_output<<<dim3(NCHUNK, NH), 256, 0, stream>>>(Qp, Kp, Vv, S0, z0, attn);
    // K5: output projection
    sgemm128<1><<<dim3(EMB / 128, L_SEQ / 128), 256, 0, stream>>>(
        attn, out_w, out_b, out, out, out, EMB);
}

// Round 2
// 482.300 us; speedup vs baseline: 1.3798x; 1.3798x over previous
//
#include <hip/hip_runtime.h>
#include <cstddef>
#include <cstdint>

#define L_SEQ 4096
#define EMB   1024
#define NH    16
#define HD    64
#define N3    3072
#define CHUNK 64
#define NCHUNK 64
#define EPS 1e-6f

typedef __attribute__((ext_vector_type(8))) short   bf16x8;
typedef __attribute__((ext_vector_type(4))) short   bf16x4;
typedef __attribute__((ext_vector_type(4))) float   floatx4;

#define AS1 __attribute__((address_space(1)))
#define AS3 __attribute__((address_space(3)))

__device__ __forceinline__ void gload_lds16(const void* g, void* l) {
    __builtin_amdgcn_global_load_lds((AS1 const unsigned int*)g,
                                     (AS3 unsigned int*)l, 16, 0, 0);
}

// round-to-nearest-even fp32 -> bf16 bits
__device__ __forceinline__ short f2bf(float f) {
    union { float f; unsigned u; } a; a.f = f;
    unsigned r = a.u + 0x7fffu + ((a.u >> 16) & 1u);
    return (short)(r >> 16);
}

// ---------------------------------------------------------------------------
// K0a: flat fp32 -> bf16 convert (8 elems/thread)
// ---------------------------------------------------------------------------
__global__ __launch_bounds__(256)
void convert_bf16(const float* __restrict__ in, short* __restrict__ out, int n8)
{
    const int i = blockIdx.x * 256 + threadIdx.x;
    if (i < n8) {
        const floatx4 a = *(const floatx4*)(in + (size_t)i * 8);
        const floatx4 b = *(const floatx4*)(in + (size_t)i * 8 + 4);
        bf16x8 o;
        o[0] = f2bf(a[0]); o[1] = f2bf(a[1]); o[2] = f2bf(a[2]); o[3] = f2bf(a[3]);
        o[4] = f2bf(b[0]); o[5] = f2bf(b[1]); o[6] = f2bf(b[2]); o[7] = f2bf(b[3]);
        *(bf16x8*)(out + (size_t)i * 8) = o;
    }
}

// ---------------------------------------------------------------------------
// K0b: transpose + convert  W (K x N fp32, row-major) -> WT (N x K bf16)
// 64x64 tile, LDS padded to 65 to break bank aliasing
// ---------------------------------------------------------------------------
__global__ __launch_bounds__(256)
void transpose_bf16(const float* __restrict__ W, short* __restrict__ WT,
                    int K, int N)
{
    __shared__ float t[64][65];
    const int bx = blockIdx.x;           // n tile
    const int by = blockIdx.y;           // k tile
    const int tid = threadIdx.x;
    const int r  = tid >> 4;             // 0..15
    const int c4 = (tid & 15) << 2;      // 0..60
#pragma unroll
    for (int s = 0; s < 4; ++s) {
        const int k = r + s * 16;
        const floatx4 v = *(const floatx4*)&W[(size_t)(by * 64 + k) * N + bx * 64 + c4];
        t[k][c4 + 0] = v[0]; t[k][c4 + 1] = v[1];
        t[k][c4 + 2] = v[2]; t[k][c4 + 3] = v[3];
    }
    __syncthreads();
#pragma unroll
    for (int s = 0; s < 4; ++s) {
        const int n = r + s * 16;
        bf16x4 o;
        o[0] = f2bf(t[c4 + 0][n]); o[1] = f2bf(t[c4 + 1][n]);
        o[2] = f2bf(t[c4 + 2][n]); o[3] = f2bf(t[c4 + 3][n]);
        *(bf16x4*)&WT[(size_t)(bx * 64 + n) * K + by * 64 + c4] = o;
    }
}

// ---------------------------------------------------------------------------
// K1/K5: bf16 MFMA GEMM (m97 structure). A: M x K bf16 row-major.
// BT: N x K bf16 row-major (B transposed). 128x128 tile, BK=32,
// 256 threads = 4 waves, each wave 64x64 via 4x4 frags of 16x16x32.
// MODE 0: bias + elu+1 on q/k, scatter fp32 to head-major Qp/Kp/Vv.
// MODE 1: bias, fp32 row-major out.
// ---------------------------------------------------------------------------
template<int MODE>
__global__ __launch_bounds__(256)
void mfma_gemm(const short* __restrict__ A, const short* __restrict__ BT,
               const float* __restrict__ bias,
               float* __restrict__ O0, float* __restrict__ O1, float* __restrict__ O2,
               int N, int K)
{
    __shared__ short Asm[128 * 32];
    __shared__ short Bsm[128 * 32];
    const int tid  = threadIdx.x;
    const int lane = tid & 63;
    const int wave = tid >> 6;
    const int wm = (wave >> 1) * 64;
    const int wn = (wave & 1) * 64;
    const int bx = blockIdx.x;           // n tile
    const int by = blockIdx.y;           // m tile
    const int frow = lane & 15;
    const int fko  = (lane >> 4) << 3;   // 0,8,16,24

    const short* Ab = A  + (size_t)(by * 128) * K;
    const short* Bb = BT + (size_t)(bx * 128) * K;

    floatx4 acc[4][4] = {};

    for (int k0 = 0; k0 < K; k0 += 32) {
#pragma unroll
        for (int q = 0; q < 2; ++q) {
            const int ia = q * 256 + tid;        // 0..511 chunks of 8 bf16
            const int row = ia >> 2;
            const int kc  = (ia & 3) << 3;
            gload_lds16(Ab + (size_t)row * K + k0 + kc, &Asm[ia << 3]);
            gload_lds16(Bb + (size_t)row * K + k0 + kc, &Bsm[ia << 3]);
        }
        __syncthreads();                          // staging complete
        bf16x8 af[4], bfv[4];
#pragma unroll
        for (int mi = 0; mi < 4; ++mi)
            af[mi] = *(const bf16x8*)&Asm[(wm + mi * 16 + frow) * 32 + fko];
#pragma unroll
        for (int ni = 0; ni < 4; ++ni)
            bfv[ni] = *(const bf16x8*)&Bsm[(wn + ni * 16 + frow) * 32 + fko];
#pragma unroll
        for (int mi = 0; mi < 4; ++mi)
#pragma unroll
            for (int ni = 0; ni < 4; ++ni)
                acc[mi][ni] = __builtin_amdgcn_mfma_f32_16x16x32_bf16(
                    af[mi], bfv[ni], acc[mi][ni], 0, 0, 0);
        __syncthreads();                          // reads done before next stage
    }

    // Epilogue. C/D layout: col = lane&15, row = (lane>>4)*4 + r
    const int rq = (lane >> 4) << 2;
#pragma unroll
    for (int ni = 0; ni < 4; ++ni) {
        const int n = bx * 128 + wn + ni * 16 + frow;
        const float bv = bias[n];
        if (MODE == 0) {
            const int rsel = n >> 10;            // 0=q 1=k 2=v (uniform per ni)
            const int nn = n & 1023;
            const int h  = nn >> 6;
            const int d  = nn & 63;
            float* base = (rsel == 0) ? O0 : (rsel == 1 ? O1 : O2);
            const bool do_elu = (rsel < 2);
#pragma unroll
            for (int mi = 0; mi < 4; ++mi) {
#pragma unroll
                for (int r = 0; r < 4; ++r) {
                    const int m = by * 128 + wm + mi * 16 + rq + r;
                    float v = acc[mi][ni][r] + bv;
                    if (do_elu) v = (v > 0.f) ? (v + 1.f) : expf(v);
                    base[((size_t)(h * L_SEQ + m)) * HD + d] = v;
                }
            }
        } else {
#pragma unroll
            for (int mi = 0; mi < 4; ++mi) {
#pragma unroll
                for (int r = 0; r < 4; ++r) {
                    const int m = by * 128 + wm + mi * 16 + rq + r;
                    O0[(size_t)m * N + n] = acc[mi][ni][r] + bv;
                }
            }
        }
    }
}

// ---------------------------------------------------------------------------
// K2: per-(head,chunk) state sums  S_c[d][e] = sum_l k'[l][d] v[l][e],
//                                  z_c[d]    = sum_l k'[l][d]
// ---------------------------------------------------------------------------
__global__ __launch_bounds__(256)
void chunk_state(const float* __restrict__ Kp, const float* __restrict__ V,
                 float* __restrict__ Sc, float* __restrict__ zc)
{
    __shared__ float Kc[CHUNK * HD];
    __shared__ float Vc[CHUNK * HD];
    const int c = blockIdx.x, h = blockIdx.y;
    const int tid = threadIdx.x;
    const floatx4* Kg = (const floatx4*)(Kp + ((size_t)h * L_SEQ + c * CHUNK) * HD);
    const floatx4* Vg = (const floatx4*)(V  + ((size_t)h * L_SEQ + c * CHUNK) * HD);
    floatx4* K4 = (floatx4*)Kc;
    floatx4* V4 = (floatx4*)Vc;
#pragma unroll
    for (int i = 0; i < 4; ++i) {
        K4[i * 256 + tid] = Kg[i * 256 + tid];
        V4[i * 256 + tid] = Vg[i * 256 + tid];
    }
    __syncthreads();
    const int d0 = (tid >> 4) << 2;
    const int e0 = (tid & 15) << 2;
    float acc[4][4] = {{0.f}};
    for (int l = 0; l < CHUNK; ++l) {
        const floatx4 kd = *(const floatx4*)&Kc[l * HD + d0];
        const floatx4 ve = *(const floatx4*)&Vc[l * HD + e0];
#pragma unroll
        for (int i = 0; i < 4; ++i)
#pragma unroll
            for (int j = 0; j < 4; ++j)
                acc[i][j] += kd[i] * ve[j];
    }
    float* Sout = Sc + ((size_t)(h * NCHUNK + c)) * HD * HD;
#pragma unroll
    for (int i = 0; i < 4; ++i) {
        floatx4 o; o[0] = acc[i][0]; o[1] = acc[i][1]; o[2] = acc[i][2]; o[3] = acc[i][3];
        *(floatx4*)&Sout[(d0 + i) * HD + e0] = o;
    }
    if (tid < HD) {
        float z = 0.f;
        for (int l = 0; l < CHUNK; ++l) z += Kc[l * HD + tid];
        zc[((size_t)(h * NCHUNK + c)) * HD + tid] = z;
    }
}

// ---------------------------------------------------------------------------
// K3: IN-PLACE exclusive prefix over chunks (per head).
// After this, Sc holds S0 (prefix-excl) and zc holds z0.
// ---------------------------------------------------------------------------
__global__ __launch_bounds__(256)
void prefix_scan(float* __restrict__ S, float* __restrict__ z)
{
    const int g = blockIdx.x * 256 + threadIdx.x;   // 0 .. NH*4096-1
    const int h  = g >> 12;
    const int de = g & 4095;
    float run = 0.f;
    for (int c = 0; c < NCHUNK; ++c) {
        const size_t idx = ((size_t)(h * NCHUNK + c)) * 4096 + de;
        const float t = S[idx];
        S[idx] = run;
        run += t;
    }
    if (g < NH * HD) {
        const int h2 = g >> 6, d = g & 63;
        float rz = 0.f;
        for (int c = 0; c < NCHUNK; ++c) {
            const size_t idx = ((size_t)(h2 * NCHUNK + c)) * HD + d;
            const float t = z[idx];
            z[idx] = rz;
            rz += t;
        }
    }
}

// ---------------------------------------------------------------------------
// K4: per-(head,chunk) intra-chunk attention; writes attn in bf16 (for K5).
// ---------------------------------------------------------------------------
#define QS 68
#define AS_ 65

__global__ __launch_bounds__(256)
void chunk_output(const float* __restrict__ Qp, const float* __restrict__ Kp,
                  const float* __restrict__ V,  const float* __restrict__ S0,
                  const float* __restrict__ z0, short* __restrict__ attn)
{
    __shared__ float Qc[CHUNK * QS];
    __shared__ float Kc[CHUNK * QS];
    __shared__ float Vc[CHUNK * QS];
    __shared__ float Asm[32 * AS_];
    __shared__ float npart[256];
    __shared__ float normL[32];
    __shared__ float z0s[HD];
    const int c = blockIdx.x, h = blockIdx.y;
    const int tid = threadIdx.x;
    const size_t rowbase = ((size_t)h * L_SEQ + c * CHUNK) * HD;
    const floatx4* Qg = (const floatx4*)(Qp + rowbase);
    const floatx4* Kg = (const floatx4*)(Kp + rowbase);
    const floatx4* Vg = (const floatx4*)(V  + rowbase);
#pragma unroll
    for (int f = tid; f < 1024; f += 256) {
        const int l = f >> 4, c4 = (f & 15) << 2;
        *(floatx4*)&Qc[l * QS + c4] = Qg[f];
        *(floatx4*)&Kc[l * QS + c4] = Kg[f];
        *(floatx4*)&Vc[l * QS + c4] = Vg[f];
    }
    if (tid < HD) z0s[tid] = z0[((size_t)(h * NCHUNK + c)) * HD + tid];
    __syncthreads();
    const float* S0g = S0 + ((size_t)(h * NCHUNK + c)) * 4096;

    for (int it = 0; it < 2; ++it) {
        {
            const int ii = tid >> 3;
            const int jg = tid & 7;
            const int i  = it * 32 + ii;
            float a[8] = {0.f, 0.f, 0.f, 0.f, 0.f, 0.f, 0.f, 0.f};
            for (int dq = 0; dq < 16; ++dq) {
                const floatx4 q4 = *(const floatx4*)&Qc[i * QS + dq * 4];
#pragma unroll
                for (int jj = 0; jj < 8; ++jj) {
                    const int j = jg * 8 + jj;
                    const floatx4 k4 = *(const floatx4*)&Kc[j * QS + dq * 4];
                    a[jj] += q4[0] * k4[0] + q4[1] * k4[1] + q4[2] * k4[2] + q4[3] * k4[3];
                }
            }
            float np = 0.f;
#pragma unroll
            for (int jj = 0; jj < 8; ++jj) {
                const int j = jg * 8 + jj;
                const float v = (j <= i) ? a[jj] : 0.f;
                Asm[ii * AS_ + j] = v;
                np += v;
            }
            npart[tid] = np;
        }
        __syncthreads();
        if (tid < 32) {
            const int i = it * 32 + tid;
            float s = 0.f;
#pragma unroll
            for (int g = 0; g < 8; ++g) s += npart[tid * 8 + g];
            for (int d = 0; d < HD; ++d) s += Qc[i * QS + d] * z0s[d];
            normL[tid] = s;
        }
        __syncthreads();
        {
            const int ii = tid >> 3;
            const int e0 = (tid & 7) * 8;
            const int i  = it * 32 + ii;
            float o[8] = {0.f, 0.f, 0.f, 0.f, 0.f, 0.f, 0.f, 0.f};
            for (int d = 0; d < HD; ++d) {
                const float qv = Qc[i * QS + d];
                const floatx4 sa = *(const floatx4*)&S0g[d * HD + e0];
                const floatx4 sb = *(const floatx4*)&S0g[d * HD + e0 + 4];
                o[0] += qv * sa[0]; o[1] += qv * sa[1]; o[2] += qv * sa[2]; o[3] += qv * sa[3];
                o[4] += qv * sb[0]; o[5] += qv * sb[1]; o[6] += qv * sb[2]; o[7] += qv * sb[3];
            }
            for (int j = 0; j < CHUNK; ++j) {
                const float av = Asm[ii * AS_ + j];
                const floatx4 va = *(const floatx4*)&Vc[j * QS + e0];
                const floatx4 vb = *(const floatx4*)&Vc[j * QS + e0 + 4];
                o[0] += av * va[0]; o[1] += av * va[1]; o[2] += av * va[2]; o[3] += av * va[3];
                o[4] += av * vb[0]; o[5] += av * vb[1]; o[6] += av * vb[2]; o[7] += av * vb[3];
            }
            const float nv = normL[ii] + EPS;
            bf16x8 pk;
#pragma unroll
            for (int j = 0; j < 8; ++j) pk[j] = f2bf(o[j] / nv);
            *(bf16x8*)(attn + ((size_t)(c * CHUNK + i)) * EMB + h * HD + e0) = pk;
        }
        __syncthreads();
    }
}

// ---------------------------------------------------------------------------
extern "C" void kernel_launch(void* const* d_in, const int* in_sizes, int n_in,
                              void* d_out, int out_size, void* d_ws, size_t ws_size,
                              hipStream_t stream)
{
    const float* x     = (const float*)d_in[0];
    const float* qkv_w = (const float*)d_in[1];
    const float* qkv_b = (const float*)d_in[2];
    const float* out_w = (const float*)d_in[3];
    const float* out_b = (const float*)d_in[4];
    float* out = (float*)d_out;

    float* ws  = (float*)d_ws;
    float* Qp  = ws;                     // H*L*D fp32
    float* Kp  = Qp + 4194304;
    float* Vv  = Kp + 4194304;
    float* Sc  = Vv + 4194304;           // becomes S0 after in-place scan
    float* zc  = Sc + 4194304;           // becomes z0
    short* xb   = (short*)(zc + 65536);  // x bf16
    short* qwt  = xb + 4194304;          // qkv_w^T bf16 (3072 x 1024)
    short* owt  = qwt + 3145728;         // out_w^T bf16 (1024 x 1024)
    short* attnb = owt + 1048576;        // attn bf16 (4096 x 1024)

    // K0: convert x; transpose+convert weights
    convert_bf16<<<dim3(2048), 256, 0, stream>>>(x, xb, 524288);
    transpose_bf16<<<dim3(N3 / 64, EMB / 64), 256, 0, stream>>>(qkv_w, qwt, EMB, N3);
    transpose_bf16<<<dim3(EMB / 64, EMB / 64), 256, 0, stream>>>(out_w, owt, EMB, EMB);
    // K1: qkv GEMM (bf16 MFMA) + bias + elu+1 + head-major scatter
    mfma_gemm<0><<<dim3(N3 / 128, L_SEQ / 128), 256, 0, stream>>>(
        xb, qwt, qkv_b, Qp, Kp, Vv, N3, EMB);
    // K2: per-chunk state sums
    chunk_state<<<dim3(NCHUNK, NH), 256, 0, stream>>>(Kp, Vv, Sc, zc);
    // K3: in-place exclusive prefix over chunks
    prefix_scan<<<dim3((NH * 4096) / 256), 256, 0, stream>>>(Sc, zc);
    // K4: intra-chunk attention, bf16 out
    chunk_output<<<dim3(NCHUNK, NH), 256, 0, stream>>>(Qp, Kp, Vv, Sc, zc, attnb);
    // K5: output projection (bf16 MFMA)
    mfma_gemm<1><<<dim3(EMB / 128, L_SEQ / 128), 256, 0, stream>>>(
        attnb, owt, out_b, out, out, out, EMB, EMB);
}

// Round 3
// 187.724 us; speedup vs baseline: 3.5451x; 2.5692x over previous
//
#include <hip/hip_runtime.h>
#include <cstddef>
#include <cstdint>

#define L_SEQ 4096
#define EMB   1024
#define NH    16
#define HD    64
#define N3    3072
#define CHUNK 64
#define NCHUNK 64
#define EPS 1e-6f

typedef __attribute__((ext_vector_type(8))) short   bf16x8;
typedef __attribute__((ext_vector_type(4))) short   bf16x4;
typedef __attribute__((ext_vector_type(4))) float   floatx4;

#define AS1 __attribute__((address_space(1)))
#define AS3 __attribute__((address_space(3)))

__device__ __forceinline__ void gload_lds16(const void* g, void* l) {
    __builtin_amdgcn_global_load_lds((AS1 const unsigned int*)g,
                                     (AS3 unsigned int*)l, 16, 0, 0);
}

// round-to-nearest-even fp32 -> bf16 bits
__device__ __forceinline__ short f2bf(float f) {
    union { float f; unsigned u; } a; a.f = f;
    unsigned r = a.u + 0x7fffu + ((a.u >> 16) & 1u);
    return (short)(r >> 16);
}
__device__ __forceinline__ float bf2f(short s) {
    union { unsigned u; float f; } a; a.u = ((unsigned)(unsigned short)s) << 16;
    return a.f;
}

// ---------------------------------------------------------------------------
// K0a: flat fp32 -> bf16 convert (8 elems/thread)
// ---------------------------------------------------------------------------
__global__ __launch_bounds__(256)
void convert_bf16(const float* __restrict__ in, short* __restrict__ out, int n8)
{
    const int i = blockIdx.x * 256 + threadIdx.x;
    if (i < n8) {
        const floatx4 a = *(const floatx4*)(in + (size_t)i * 8);
        const floatx4 b = *(const floatx4*)(in + (size_t)i * 8 + 4);
        bf16x8 o;
        o[0] = f2bf(a[0]); o[1] = f2bf(a[1]); o[2] = f2bf(a[2]); o[3] = f2bf(a[3]);
        o[4] = f2bf(b[0]); o[5] = f2bf(b[1]); o[6] = f2bf(b[2]); o[7] = f2bf(b[3]);
        *(bf16x8*)(out + (size_t)i * 8) = o;
    }
}

// ---------------------------------------------------------------------------
// K0b: transpose + convert  W (K x N fp32) -> WT (N x K bf16)
// ---------------------------------------------------------------------------
__global__ __launch_bounds__(256)
void transpose_bf16(const float* __restrict__ W, short* __restrict__ WT,
                    int K, int N)
{
    __shared__ float t[64][65];
    const int bx = blockIdx.x, by = blockIdx.y;
    const int tid = threadIdx.x;
    const int r  = tid >> 4;
    const int c4 = (tid & 15) << 2;
#pragma unroll
    for (int s = 0; s < 4; ++s) {
        const int k = r + s * 16;
        const floatx4 v = *(const floatx4*)&W[(size_t)(by * 64 + k) * N + bx * 64 + c4];
        t[k][c4 + 0] = v[0]; t[k][c4 + 1] = v[1];
        t[k][c4 + 2] = v[2]; t[k][c4 + 3] = v[3];
    }
    __syncthreads();
#pragma unroll
    for (int s = 0; s < 4; ++s) {
        const int n = r + s * 16;
        bf16x4 o;
        o[0] = f2bf(t[c4 + 0][n]); o[1] = f2bf(t[c4 + 1][n]);
        o[2] = f2bf(t[c4 + 2][n]); o[3] = f2bf(t[c4 + 3][n]);
        *(bf16x4*)&WT[(size_t)(bx * 64 + n) * K + by * 64 + c4] = o;
    }
}

// ---------------------------------------------------------------------------
// K1/K5: bf16 MFMA GEMM (m97 structure), 128x128 tile, BK=32.
// MODE 0: bias + elu+1 on q/k, scatter bf16 to head-major Qb/Kb/Vb.
// MODE 1: bias, fp32 row-major OF.
// ---------------------------------------------------------------------------
template<int MODE>
__global__ __launch_bounds__(256)
void mfma_gemm(const short* __restrict__ A, const short* __restrict__ BT,
               const float* __restrict__ bias,
               short* __restrict__ OQ, short* __restrict__ OK, short* __restrict__ OV,
               float* __restrict__ OF, int N, int K)
{
    __shared__ short Asm[128 * 32];
    __shared__ short Bsm[128 * 32];
    const int tid  = threadIdx.x;
    const int lane = tid & 63;
    const int wave = tid >> 6;
    const int wm = (wave >> 1) * 64;
    const int wn = (wave & 1) * 64;
    const int bx = blockIdx.x;
    const int by = blockIdx.y;
    const int frow = lane & 15;
    const int fko  = (lane >> 4) << 3;

    const short* Ab = A  + (size_t)(by * 128) * K;
    const short* Bb = BT + (size_t)(bx * 128) * K;

    floatx4 acc[4][4] = {};

    for (int k0 = 0; k0 < K; k0 += 32) {
#pragma unroll
        for (int q = 0; q < 2; ++q) {
            const int ia = q * 256 + tid;
            const int row = ia >> 2;
            const int kc  = (ia & 3) << 3;
            gload_lds16(Ab + (size_t)row * K + k0 + kc, &Asm[ia << 3]);
            gload_lds16(Bb + (size_t)row * K + k0 + kc, &Bsm[ia << 3]);
        }
        __syncthreads();
        bf16x8 af[4], bfv[4];
#pragma unroll
        for (int mi = 0; mi < 4; ++mi)
            af[mi] = *(const bf16x8*)&Asm[(wm + mi * 16 + frow) * 32 + fko];
#pragma unroll
        for (int ni = 0; ni < 4; ++ni)
            bfv[ni] = *(const bf16x8*)&Bsm[(wn + ni * 16 + frow) * 32 + fko];
#pragma unroll
        for (int mi = 0; mi < 4; ++mi)
#pragma unroll
            for (int ni = 0; ni < 4; ++ni)
                acc[mi][ni] = __builtin_amdgcn_mfma_f32_16x16x32_bf16(
                    af[mi], bfv[ni], acc[mi][ni], 0, 0, 0);
        __syncthreads();
    }

    const int rq = (lane >> 4) << 2;
#pragma unroll
    for (int ni = 0; ni < 4; ++ni) {
        const int n = bx * 128 + wn + ni * 16 + frow;
        const float bv = bias[n];
        if (MODE == 0) {
            const int rsel = n >> 10;            // 0=q 1=k 2=v
            const int nn = n & 1023;
            const int h  = nn >> 6;
            const int d  = nn & 63;
            short* base = (rsel == 0) ? OQ : (rsel == 1 ? OK : OV);
            const bool do_elu = (rsel < 2);
#pragma unroll
            for (int mi = 0; mi < 4; ++mi) {
#pragma unroll
                for (int r = 0; r < 4; ++r) {
                    const int m = by * 128 + wm + mi * 16 + rq + r;
                    float v = acc[mi][ni][r] + bv;
                    if (do_elu) v = (v > 0.f) ? (v + 1.f) : expf(v);
                    base[((size_t)(h * L_SEQ + m)) * HD + d] = f2bf(v);
                }
            }
        } else {
#pragma unroll
            for (int mi = 0; mi < 4; ++mi) {
#pragma unroll
                for (int r = 0; r < 4; ++r) {
                    const int m = by * 128 + wm + mi * 16 + rq + r;
                    OF[(size_t)m * N + n] = acc[mi][ni][r] + bv;
                }
            }
        }
    }
}

// ---------------------------------------------------------------------------
// K2: per-(head,chunk) state sums, TRANSPOSED store:
//   ScT[(h,c)][e][d] = sum_l k'[l][d] v[l][e];  zc[(h,c)][d] = sum_l k'[l][d]
// ---------------------------------------------------------------------------
__global__ __launch_bounds__(256)
void chunk_state(const short* __restrict__ Kb, const short* __restrict__ Vb,
                 float* __restrict__ ScT, float* __restrict__ zc)
{
    __shared__ float Kc[CHUNK * HD];
    __shared__ float Vc[CHUNK * HD];
    const int c = blockIdx.x, h = blockIdx.y;
    const int tid = threadIdx.x;
    const short* Kg = Kb + ((size_t)h * L_SEQ + (size_t)c * CHUNK) * HD;
    const short* Vg = Vb + ((size_t)h * L_SEQ + (size_t)c * CHUNK) * HD;
#pragma unroll
    for (int q = 0; q < 2; ++q) {
        const int idx = q * 256 + tid;          // 512 chunks of 8
        const bf16x8 kv = *(const bf16x8*)&Kg[idx * 8];
        const bf16x8 vv = *(const bf16x8*)&Vg[idx * 8];
#pragma unroll
        for (int j = 0; j < 8; ++j) {
            Kc[idx * 8 + j] = bf2f(kv[j]);
            Vc[idx * 8 + j] = bf2f(vv[j]);
        }
    }
    __syncthreads();
    const int e0 = (tid >> 4) << 2;
    const int d0 = (tid & 15) << 2;
    float acc[4][4] = {{0.f}};
    for (int l = 0; l < CHUNK; ++l) {
        const floatx4 ve = *(const floatx4*)&Vc[l * HD + e0];
        const floatx4 kd = *(const floatx4*)&Kc[l * HD + d0];
#pragma unroll
        for (int a = 0; a < 4; ++a)
#pragma unroll
            for (int b = 0; b < 4; ++b)
                acc[a][b] += ve[a] * kd[b];
    }
    float* Sout = ScT + ((size_t)(h * NCHUNK + c)) * HD * HD;
#pragma unroll
    for (int a = 0; a < 4; ++a) {
        floatx4 o; o[0] = acc[a][0]; o[1] = acc[a][1]; o[2] = acc[a][2]; o[3] = acc[a][3];
        *(floatx4*)&Sout[(e0 + a) * HD + d0] = o;
    }
    if (tid < HD) {
        float z = 0.f;
        for (int l = 0; l < CHUNK; ++l) z += Kc[l * HD + tid];
        zc[((size_t)(h * NCHUNK + c)) * HD + tid] = z;
    }
}

// ---------------------------------------------------------------------------
// K3: exclusive prefix over chunks; emits bf16 S0b in EXTENDED transposed
// layout per (h,c): 65 rows x 64 cols; rows 0..63 = S0^T[e][d], row 64 = z0[d].
// ---------------------------------------------------------------------------
__global__ __launch_bounds__(256)
void prefix_scan(const float* __restrict__ ScT, const float* __restrict__ zc,
                 short* __restrict__ S0b)
{
    const int g = blockIdx.x * 256 + threadIdx.x;   // NH*4096 threads
    const int h  = g >> 12;
    const int ed = g & 4095;                        // e*64 + d
    const int e  = ed >> 6;
    const int d  = ed & 63;
    float run = 0.f;
    for (int c = 0; c < NCHUNK; ++c) {
        S0b[((size_t)(h * NCHUNK + c) * 65 + e) * 64 + d] = f2bf(run);
        run += ScT[((size_t)(h * NCHUNK + c)) * 4096 + ed];
    }
    if (g < NH * HD) {
        const int h2 = g >> 6, d2 = g & 63;
        float rz = 0.f;
        for (int c = 0; c < NCHUNK; ++c) {
            S0b[((size_t)(h2 * NCHUNK + c) * 65 + 64) * 64 + d2] = f2bf(rz);
            rz += zc[((size_t)(h2 * NCHUNK + c)) * HD + d2];
        }
    }
}

// ---------------------------------------------------------------------------
// K4: per-(head,chunk) intra-chunk attention, all-MFMA.
//   A = mask(Q'K'^T); O_ext = A @ V_ext + Q' @ S0_ext  (N=80, col 64 = norm)
//   attn[c*64+i][h*64+e] = O[i][e] / (O[i][64] + EPS)   (bf16)
// LDS row stride 72 bf16 (144 B): bank rotation period 8 -> 2-way max (free).
// ---------------------------------------------------------------------------
#define SP 72

__global__ __launch_bounds__(256)
void chunk_attn(const short* __restrict__ Qb, const short* __restrict__ Kb,
                const short* __restrict__ Vb, const short* __restrict__ S0b,
                short* __restrict__ attn)
{
    __shared__ __align__(16) short Qs[64 * SP];
    __shared__ __align__(16) short Ks[64 * SP];
    __shared__ __align__(16) short As[64 * SP];
    __shared__ __align__(16) short Vs[80 * SP];   // V^T, row 64 = ones; 65..79 unused
    __shared__ __align__(16) short Ss[80 * SP];   // S0^T ext; 65..79 unused
    const int c = blockIdx.x, h = blockIdx.y;
    const int tid = threadIdx.x, lane = tid & 63, wave = tid >> 6;
    const size_t rb = ((size_t)h * L_SEQ + (size_t)c * CHUNK) * HD;
    const short* Qg = Qb + rb;
    const short* Kg = Kb + rb;
    const short* Vg = Vb + rb;
    const short* Sg = S0b + (size_t)(h * NCHUNK + c) * 65 * 64;

#pragma unroll
    for (int q = 0; q < 2; ++q) {
        const int idx = q * 256 + tid;            // 512 chunks of 8
        const int row = idx >> 3, c8 = (idx & 7) << 3;
        *(bf16x8*)&Qs[row * SP + c8] = *(const bf16x8*)&Qg[row * 64 + c8];
        *(bf16x8*)&Ks[row * SP + c8] = *(const bf16x8*)&Kg[row * 64 + c8];
        const bf16x8 vv = *(const bf16x8*)&Vg[row * 64 + c8];
#pragma unroll
        for (int j = 0; j < 8; ++j) Vs[(c8 + j) * SP + row] = vv[j];   // V^T
    }
    if (tid < 64) Vs[64 * SP + tid] = (short)0x3F80;                   // ones row
    for (int idx = tid; idx < 520; idx += 256) {                       // 65*64/8
        const int row = idx >> 3, c8 = (idx & 7) << 3;
        *(bf16x8*)&Ss[row * SP + c8] = *(const bf16x8*)&Sg[row * 64 + c8];
    }
    __syncthreads();

    const int frow = lane & 15;
    const int quad = lane >> 4;
    const int fko  = quad << 3;
    const int wm   = wave << 4;            // wave's 16-row m-tile

    const bf16x8 qf0 = *(const bf16x8*)&Qs[(wm + frow) * SP + fko];
    const bf16x8 qf1 = *(const bf16x8*)&Qs[(wm + frow) * SP + 32 + fko];

    // ---- QK^T (M=16, N=64, K=64) ----
    floatx4 sacc[4] = {};
#pragma unroll
    for (int n = 0; n < 4; ++n) {
        const bf16x8 kf0 = *(const bf16x8*)&Ks[(n * 16 + frow) * SP + fko];
        const bf16x8 kf1 = *(const bf16x8*)&Ks[(n * 16 + frow) * SP + 32 + fko];
        sacc[n] = __builtin_amdgcn_mfma_f32_16x16x32_bf16(qf0, kf0, sacc[n], 0, 0, 0);
        sacc[n] = __builtin_amdgcn_mfma_f32_16x16x32_bf16(qf1, kf1, sacc[n], 0, 0, 0);
    }
    // mask + bf16 A to LDS (each wave touches only its own 16 rows)
#pragma unroll
    for (int n = 0; n < 4; ++n)
#pragma unroll
        for (int r = 0; r < 4; ++r) {
            const int i = wm + quad * 4 + r;
            const int j = n * 16 + frow;
            As[i * SP + j] = (j <= i) ? f2bf(sacc[n][r]) : (short)0;
        }
    __syncthreads();

    // ---- O_ext = A @ V_ext + Q @ S0_ext  (M=16, N=80, K=64 each) ----
    const bf16x8 af0 = *(const bf16x8*)&As[(wm + frow) * SP + fko];
    const bf16x8 af1 = *(const bf16x8*)&As[(wm + frow) * SP + 32 + fko];
    floatx4 oacc[5] = {};
#pragma unroll
    for (int n = 0; n < 5; ++n) {
        const bf16x8 vf0 = *(const bf16x8*)&Vs[(n * 16 + frow) * SP + fko];
        const bf16x8 vf1 = *(const bf16x8*)&Vs[(n * 16 + frow) * SP + 32 + fko];
        oacc[n] = __builtin_amdgcn_mfma_f32_16x16x32_bf16(af0, vf0, oacc[n], 0, 0, 0);
        oacc[n] = __builtin_amdgcn_mfma_f32_16x16x32_bf16(af1, vf1, oacc[n], 0, 0, 0);
        const bf16x8 sf0 = *(const bf16x8*)&Ss[(n * 16 + frow) * SP + fko];
        const bf16x8 sf1 = *(const bf16x8*)&Ss[(n * 16 + frow) * SP + 32 + fko];
        oacc[n] = __builtin_amdgcn_mfma_f32_16x16x32_bf16(qf0, sf0, oacc[n], 0, 0, 0);
        oacc[n] = __builtin_amdgcn_mfma_f32_16x16x32_bf16(qf1, sf1, oacc[n], 0, 0, 0);
    }

    // ---- normalize (norm = col 64 -> frow==0 lane of tile 4) & store ----
#pragma unroll
    for (int r = 0; r < 4; ++r) {
        const float norm = __shfl(oacc[4][r], lane & 48) + EPS;
        const float inv = 1.f / norm;
        const int i = wm + quad * 4 + r;
        short* dst = attn + (size_t)(c * CHUNK + i) * EMB + h * HD;
#pragma unroll
        for (int n = 0; n < 4; ++n)
            dst[n * 16 + frow] = f2bf(oacc[n][r] * inv);
    }
}

// ---------------------------------------------------------------------------
extern "C" void kernel_launch(void* const* d_in, const int* in_sizes, int n_in,
                              void* d_out, int out_size, void* d_ws, size_t ws_size,
                              hipStream_t stream)
{
    const float* x     = (const float*)d_in[0];
    const float* qkv_w = (const float*)d_in[1];
    const float* qkv_b = (const float*)d_in[2];
    const float* out_w = (const float*)d_in[3];
    const float* out_b = (const float*)d_in[4];
    float* out = (float*)d_out;

    short* ws    = (short*)d_ws;
    short* Qb    = ws;                   // 4194304 bf16 each, head-major
    short* Kb    = Qb + 4194304;
    short* Vb    = Kb + 4194304;
    short* xb    = Vb + 4194304;
    short* qwt   = xb + 4194304;         // 3072 x 1024
    short* owt   = qwt + 3145728;        // 1024 x 1024
    short* attnb = owt + 1048576;        // 4096 x 1024
    short* S0b   = attnb + 4194304;      // 1024 * 65 * 64
    float* ScT   = (float*)(S0b + 4259840);
    float* zc    = ScT + 4194304;

    convert_bf16<<<dim3(2048), 256, 0, stream>>>(x, xb, 524288);
    transpose_bf16<<<dim3(N3 / 64, EMB / 64), 256, 0, stream>>>(qkv_w, qwt, EMB, N3);
    transpose_bf16<<<dim3(EMB / 64, EMB / 64), 256, 0, stream>>>(out_w, owt, EMB, EMB);
    mfma_gemm<0><<<dim3(N3 / 128, L_SEQ / 128), 256, 0, stream>>>(
        xb, qwt, qkv_b, Qb, Kb, Vb, nullptr, N3, EMB);
    chunk_state<<<dim3(NCHUNK, NH), 256, 0, stream>>>(Kb, Vb, ScT, zc);
    prefix_scan<<<dim3((NH * 4096) / 256), 256, 0, stream>>>(ScT, zc, S0b);
    chunk_attn<<<dim3(NCHUNK, NH), 256, 0, stream>>>(Qb, Kb, Vb, S0b, attnb);
    mfma_gemm<1><<<dim3(EMB / 128, L_SEQ / 128), 256, 0, stream>>>(
        attnb, owt, out_b, nullptr, nullptr, nullptr, out, EMB, EMB);
}

// Round 4
// 179.885 us; speedup vs baseline: 3.6996x; 1.0436x over previous
//
#include <hip/hip_runtime.h>
#include <cstddef>
#include <cstdint>

#define L_SEQ 4096
#define EMB   1024
#define NH    16
#define HD    64
#define N3    3072
#define CHUNK 64
#define NCHUNK 64
#define EPS 1e-6f

typedef __attribute__((ext_vector_type(8))) short   bf16x8;
typedef __attribute__((ext_vector_type(4))) short   bf16x4;
typedef __attribute__((ext_vector_type(4))) float   floatx4;

#define AS1 __attribute__((address_space(1)))
#define AS3 __attribute__((address_space(3)))

__device__ __forceinline__ void gload_lds16(const void* g, void* l) {
    __builtin_amdgcn_global_load_lds((AS1 const unsigned int*)g,
                                     (AS3 unsigned int*)l, 16, 0, 0);
}

// round-to-nearest-even fp32 -> bf16 bits
__device__ __forceinline__ short f2bf(float f) {
    union { float f; unsigned u; } a; a.f = f;
    unsigned r = a.u + 0x7fffu + ((a.u >> 16) & 1u);
    return (short)(r >> 16);
}
__device__ __forceinline__ float bf2f(short s) {
    union { unsigned u; float f; } a; a.u = ((unsigned)(unsigned short)s) << 16;
    return a.f;
}

// ---------------------------------------------------------------------------
// K0: fused prep — blocks [0,2048): x->bf16; [2048,2816): qkv_w^T;
// [2816,3072): out_w^T.  (one launch instead of three)
// ---------------------------------------------------------------------------
__device__ __forceinline__ void transpose_tile(const float* __restrict__ W,
                                               short* __restrict__ WT,
                                               int K, int N, int bx, int by,
                                               float (*t)[65], int tid)
{
    const int r  = tid >> 4;
    const int c4 = (tid & 15) << 2;
#pragma unroll
    for (int s = 0; s < 4; ++s) {
        const int k = r + s * 16;
        const floatx4 v = *(const floatx4*)&W[(size_t)(by * 64 + k) * N + bx * 64 + c4];
        t[k][c4 + 0] = v[0]; t[k][c4 + 1] = v[1];
        t[k][c4 + 2] = v[2]; t[k][c4 + 3] = v[3];
    }
    __syncthreads();
#pragma unroll
    for (int s = 0; s < 4; ++s) {
        const int n = r + s * 16;
        bf16x4 o;
        o[0] = f2bf(t[c4 + 0][n]); o[1] = f2bf(t[c4 + 1][n]);
        o[2] = f2bf(t[c4 + 2][n]); o[3] = f2bf(t[c4 + 3][n]);
        *(bf16x4*)&WT[(size_t)(bx * 64 + n) * K + by * 64 + c4] = o;
    }
}

__global__ __launch_bounds__(256)
void prep(const float* __restrict__ x, short* __restrict__ xb,
          const float* __restrict__ qkv_w, short* __restrict__ qwt,
          const float* __restrict__ out_w, short* __restrict__ owt)
{
    __shared__ float t[64][65];
    const int b = blockIdx.x;
    const int tid = threadIdx.x;
    if (b < 2048) {
        const int i = b * 256 + tid;            // 524288 groups of 8
        const floatx4 a = *(const floatx4*)(x + (size_t)i * 8);
        const floatx4 c = *(const floatx4*)(x + (size_t)i * 8 + 4);
        bf16x8 o;
        o[0] = f2bf(a[0]); o[1] = f2bf(a[1]); o[2] = f2bf(a[2]); o[3] = f2bf(a[3]);
        o[4] = f2bf(c[0]); o[5] = f2bf(c[1]); o[6] = f2bf(c[2]); o[7] = f2bf(c[3]);
        *(bf16x8*)(xb + (size_t)i * 8) = o;
    } else if (b < 2048 + 768) {
        const int u = b - 2048;                 // qkv_w: K=1024, N=3072
        transpose_tile(qkv_w, qwt, EMB, N3, u % 48, u / 48, t, tid);
    } else {
        const int u = b - 2816;                 // out_w: 1024x1024
        transpose_tile(out_w, owt, EMB, EMB, u & 15, u >> 4, t, tid);
    }
}

// ---------------------------------------------------------------------------
// K1/K5: bf16 MFMA GEMM (m97 structure), 128x128 tile, BK=32.
// MODE 0: bias + elu+1 on q/k, LDS-repacked coalesced bf16x8 scatter to
//         head-major Qb/Kb/Vb.
// MODE 1: bias, fp32 row-major OF (direct dword stores, 64B/16-lane = clean).
// ---------------------------------------------------------------------------
#define CST 136   // epilogue LDS row stride (bf16): 272B rows, 16B-aligned

template<int MODE>
__global__ __launch_bounds__(256)
void mfma_gemm(const short* __restrict__ A, const short* __restrict__ BT,
               const float* __restrict__ bias,
               short* __restrict__ OQ, short* __restrict__ OK, short* __restrict__ OV,
               float* __restrict__ OF, int N, int K)
{
    __shared__ __align__(16) short smem[128 * CST];   // 34.8 KB; staging uses 16 KB
    short* Asm = smem;
    short* Bsm = smem + 4096;
    const int tid  = threadIdx.x;
    const int lane = tid & 63;
    const int wave = tid >> 6;
    const int wm = (wave >> 1) * 64;
    const int wn = (wave & 1) * 64;
    const int bx = blockIdx.x;
    const int by = blockIdx.y;
    const int frow = lane & 15;
    const int fko  = (lane >> 4) << 3;

    const short* Ab = A  + (size_t)(by * 128) * K;
    const short* Bb = BT + (size_t)(bx * 128) * K;

    floatx4 acc[4][4] = {};

    for (int k0 = 0; k0 < K; k0 += 32) {
#pragma unroll
        for (int q = 0; q < 2; ++q) {
            const int ia = q * 256 + tid;
            const int row = ia >> 2;
            const int kc  = (ia & 3) << 3;
            gload_lds16(Ab + (size_t)row * K + k0 + kc, &Asm[ia << 3]);
            gload_lds16(Bb + (size_t)row * K + k0 + kc, &Bsm[ia << 3]);
        }
        __syncthreads();
        bf16x8 af[4], bfv[4];
#pragma unroll
        for (int mi = 0; mi < 4; ++mi)
            af[mi] = *(const bf16x8*)&Asm[(wm + mi * 16 + frow) * 32 + fko];
#pragma unroll
        for (int ni = 0; ni < 4; ++ni)
            bfv[ni] = *(const bf16x8*)&Bsm[(wn + ni * 16 + frow) * 32 + fko];
#pragma unroll
        for (int mi = 0; mi < 4; ++mi)
#pragma unroll
            for (int ni = 0; ni < 4; ++ni)
                acc[mi][ni] = __builtin_amdgcn_mfma_f32_16x16x32_bf16(
                    af[mi], bfv[ni], acc[mi][ni], 0, 0, 0);
        __syncthreads();
    }

    const int rq = (lane >> 4) << 2;
    if (MODE == 0) {
        // bias + elu -> bf16 into LDS tile [m][n], then coalesced scatter
#pragma unroll
        for (int ni = 0; ni < 4; ++ni) {
            const int n = bx * 128 + wn + ni * 16 + frow;
            const float bv = bias[n];
            const bool do_elu = (n >> 10) < 2;
#pragma unroll
            for (int mi = 0; mi < 4; ++mi)
#pragma unroll
                for (int r = 0; r < 4; ++r) {
                    float v = acc[mi][ni][r] + bv;
                    if (do_elu) v = (v > 0.f) ? (v + 1.f) : __expf(v);
                    smem[(wm + mi * 16 + rq + r) * CST + wn + ni * 16 + frow] = f2bf(v);
                }
        }
        __syncthreads();
#pragma unroll
        for (int t = 0; t < 8; ++t) {
            const int idx = t * 256 + tid;        // 2048 groups of 8
            const int mm = idx >> 4;
            const int c8 = (idx & 15) << 3;
            const bf16x8 val = *(const bf16x8*)&smem[mm * CST + c8];
            const int n0 = bx * 128 + c8;
            const int rsel = n0 >> 10;            // 0=q 1=k 2=v
            const int h  = (n0 & 1023) >> 6;
            const int d  = n0 & 63;
            short* base = (rsel == 0) ? OQ : (rsel == 1 ? OK : OV);
            *(bf16x8*)&base[((size_t)(h * L_SEQ + by * 128 + mm)) * HD + d] = val;
        }
    } else {
#pragma unroll
        for (int ni = 0; ni < 4; ++ni) {
            const int n = bx * 128 + wn + ni * 16 + frow;
            const float bv = bias[n];
#pragma unroll
            for (int mi = 0; mi < 4; ++mi)
#pragma unroll
                for (int r = 0; r < 4; ++r) {
                    const int m = by * 128 + wm + mi * 16 + rq + r;
                    OF[(size_t)m * N + n] = acc[mi][ni][r] + bv;
                }
        }
    }
}

// ---------------------------------------------------------------------------
// K2: per-(head,chunk) state sums, TRANSPOSED bf16 store:
//   ScTb[(h,c)][e][d] = sum_l k'[l][d] v[l][e];  zc[(h,c)][d] = sum_l k'[l][d]
// ---------------------------------------------------------------------------
__global__ __launch_bounds__(256)
void chunk_state(const short* __restrict__ Kb, const short* __restrict__ Vb,
                 short* __restrict__ ScTb, float* __restrict__ zc)
{
    __shared__ float Kc[CHUNK * HD];
    __shared__ float Vc[CHUNK * HD];
    const int c = blockIdx.x, h = blockIdx.y;
    const int tid = threadIdx.x;
    const short* Kg = Kb + ((size_t)h * L_SEQ + (size_t)c * CHUNK) * HD;
    const short* Vg = Vb + ((size_t)h * L_SEQ + (size_t)c * CHUNK) * HD;
#pragma unroll
    for (int q = 0; q < 2; ++q) {
        const int idx = q * 256 + tid;
        const bf16x8 kv = *(const bf16x8*)&Kg[idx * 8];
        const bf16x8 vv = *(const bf16x8*)&Vg[idx * 8];
#pragma unroll
        for (int j = 0; j < 8; ++j) {
            Kc[idx * 8 + j] = bf2f(kv[j]);
            Vc[idx * 8 + j] = bf2f(vv[j]);
        }
    }
    __syncthreads();
    const int e0 = (tid >> 4) << 2;
    const int d0 = (tid & 15) << 2;
    float acc[4][4] = {{0.f}};
    for (int l = 0; l < CHUNK; ++l) {
        const floatx4 ve = *(const floatx4*)&Vc[l * HD + e0];
        const floatx4 kd = *(const floatx4*)&Kc[l * HD + d0];
#pragma unroll
        for (int a = 0; a < 4; ++a)
#pragma unroll
            for (int b = 0; b < 4; ++b)
                acc[a][b] += ve[a] * kd[b];
    }
    short* Sout = ScTb + (size_t)(h * NCHUNK + c) * 4096;
#pragma unroll
    for (int a = 0; a < 4; ++a) {
        bf16x4 o;
        o[0] = f2bf(acc[a][0]); o[1] = f2bf(acc[a][1]);
        o[2] = f2bf(acc[a][2]); o[3] = f2bf(acc[a][3]);
        *(bf16x4*)&Sout[(e0 + a) * HD + d0] = o;
    }
    if (tid < HD) {
        float z = 0.f;
        for (int l = 0; l < CHUNK; ++l) z += Kc[l * HD + tid];
        zc[((size_t)(h * NCHUNK + c)) * HD + tid] = z;
    }
}

// ---------------------------------------------------------------------------
// K3: exclusive prefix over chunks, 8-deep batched loads (latency hiding).
// Emits bf16 S0b per (h,c): 65 rows x 64; rows 0..63 = S0^T, row 64 = z0.
// ---------------------------------------------------------------------------
__global__ __launch_bounds__(256)
void prefix_scan(const short* __restrict__ ScTb, const float* __restrict__ zc,
                 short* __restrict__ S0b)
{
    const int g = blockIdx.x * 256 + threadIdx.x;   // NH*4096 threads
    const int h  = g >> 12;
    const int ed = g & 4095;
    const int e  = ed >> 6;
    const int d  = ed & 63;
    const short* src = ScTb + (size_t)h * NCHUNK * 4096 + ed;
    float run = 0.f;
    for (int cb = 0; cb < NCHUNK; cb += 8) {
        short v[8];
#pragma unroll
        for (int u = 0; u < 8; ++u) v[u] = src[(size_t)(cb + u) * 4096];
#pragma unroll
        for (int u = 0; u < 8; ++u) {
            S0b[((size_t)((h * NCHUNK + cb + u) * 65 + e)) * 64 + d] = f2bf(run);
            run += bf2f(v[u]);
        }
    }
    if (g < NH * HD) {
        const int h2 = g >> 6, d2 = g & 63;
        float rz = 0.f;
        for (int cb = 0; cb < NCHUNK; cb += 8) {
            float w[8];
#pragma unroll
            for (int u = 0; u < 8; ++u)
                w[u] = zc[((size_t)(h2 * NCHUNK + cb + u)) * HD + d2];
#pragma unroll
            for (int u = 0; u < 8; ++u) {
                S0b[((size_t)((h2 * NCHUNK + cb + u) * 65 + 64)) * 64 + d2] = f2bf(rz);
                rz += w[u];
            }
        }
    }
}

// ---------------------------------------------------------------------------
// K4: per-(head,chunk) intra-chunk attention, all-MFMA.
//   A = mask(Q'K'^T); O_ext = A @ V_ext + Q' @ S0_ext  (N=80, col 64 = norm)
//   attn[c*64+i][h*64+e] = O[i][e] / (O[i][64] + EPS)   (bf16, LDS-repacked)
// ---------------------------------------------------------------------------
#define SP 72

__global__ __launch_bounds__(256)
void chunk_attn(const short* __restrict__ Qb, const short* __restrict__ Kb,
                const short* __restrict__ Vb, const short* __restrict__ S0b,
                short* __restrict__ attn)
{
    __shared__ __align__(16) short Qs[64 * SP];
    __shared__ __align__(16) short Ks[64 * SP];
    __shared__ __align__(16) short As[64 * SP];
    __shared__ __align__(16) short Vs[80 * SP];
    __shared__ __align__(16) short Ss[80 * SP];
    const int c = blockIdx.x, h = blockIdx.y;
    const int tid = threadIdx.x, lane = tid & 63, wave = tid >> 6;
    const size_t rb = ((size_t)h * L_SEQ + (size_t)c * CHUNK) * HD;
    const short* Qg = Qb + rb;
    const short* Kg = Kb + rb;
    const short* Vg = Vb + rb;
    const short* Sg = S0b + (size_t)(h * NCHUNK + c) * 65 * 64;

#pragma unroll
    for (int q = 0; q < 2; ++q) {
        const int idx = q * 256 + tid;
        const int row = idx >> 3, c8 = (idx & 7) << 3;
        *(bf16x8*)&Qs[row * SP + c8] = *(const bf16x8*)&Qg[row * 64 + c8];
        *(bf16x8*)&Ks[row * SP + c8] = *(const bf16x8*)&Kg[row * 64 + c8];
        const bf16x8 vv = *(const bf16x8*)&Vg[row * 64 + c8];
#pragma unroll
        for (int j = 0; j < 8; ++j) Vs[(c8 + j) * SP + row] = vv[j];   // V^T
    }
    if (tid < 64) Vs[64 * SP + tid] = (short)0x3F80;                   // ones row
    for (int idx = tid; idx < 520; idx += 256) {
        const int row = idx >> 3, c8 = (idx & 7) << 3;
        *(bf16x8*)&Ss[row * SP + c8] = *(const bf16x8*)&Sg[row * 64 + c8];
    }
    __syncthreads();

    const int frow = lane & 15;
    const int quad = lane >> 4;
    const int fko  = quad << 3;
    const int wm   = wave << 4;

    const bf16x8 qf0 = *(const bf16x8*)&Qs[(wm + frow) * SP + fko];
    const bf16x8 qf1 = *(const bf16x8*)&Qs[(wm + frow) * SP + 32 + fko];

    // ---- QK^T (M=16, N=64, K=64) ----
    floatx4 sacc[4] = {};
#pragma unroll
    for (int n = 0; n < 4; ++n) {
        const bf16x8 kf0 = *(const bf16x8*)&Ks[(n * 16 + frow) * SP + fko];
        const bf16x8 kf1 = *(const bf16x8*)&Ks[(n * 16 + frow) * SP + 32 + fko];
        sacc[n] = __builtin_amdgcn_mfma_f32_16x16x32_bf16(qf0, kf0, sacc[n], 0, 0, 0);
        sacc[n] = __builtin_amdgcn_mfma_f32_16x16x32_bf16(qf1, kf1, sacc[n], 0, 0, 0);
    }
#pragma unroll
    for (int n = 0; n < 4; ++n)
#pragma unroll
        for (int r = 0; r < 4; ++r) {
            const int i = wm + quad * 4 + r;
            const int j = n * 16 + frow;
            As[i * SP + j] = (j <= i) ? f2bf(sacc[n][r]) : (short)0;
        }
    __syncthreads();

    // ---- O_ext = A @ V_ext + Q @ S0_ext ----
    const bf16x8 af0 = *(const bf16x8*)&As[(wm + frow) * SP + fko];
    const bf16x8 af1 = *(const bf16x8*)&As[(wm + frow) * SP + 32 + fko];
    floatx4 oacc[5] = {};
#pragma unroll
    for (int n = 0; n < 5; ++n) {
        const bf16x8 vf0 = *(const bf16x8*)&Vs[(n * 16 + frow) * SP + fko];
        const bf16x8 vf1 = *(const bf16x8*)&Vs[(n * 16 + frow) * SP + 32 + fko];
        oacc[n] = __builtin_amdgcn_mfma_f32_16x16x32_bf16(af0, vf0, oacc[n], 0, 0, 0);
        oacc[n] = __builtin_amdgcn_mfma_f32_16x16x32_bf16(af1, vf1, oacc[n], 0, 0, 0);
        const bf16x8 sf0 = *(const bf16x8*)&Ss[(n * 16 + frow) * SP + fko];
        const bf16x8 sf1 = *(const bf16x8*)&Ss[(n * 16 + frow) * SP + 32 + fko];
        oacc[n] = __builtin_amdgcn_mfma_f32_16x16x32_bf16(qf0, sf0, oacc[n], 0, 0, 0);
        oacc[n] = __builtin_amdgcn_mfma_f32_16x16x32_bf16(qf1, sf1, oacc[n], 0, 0, 0);
    }

    // ---- normalize into As (own rows only -> no barrier needed), repack ----
#pragma unroll
    for (int r = 0; r < 4; ++r) {
        const float norm = __shfl(oacc[4][r], lane & 48) + EPS;
        const float inv = 1.f / norm;
        const int i = wm + quad * 4 + r;
#pragma unroll
        for (int n = 0; n < 4; ++n)
            As[i * SP + n * 16 + frow] = f2bf(oacc[n][r] * inv);
    }
    __syncthreads();
#pragma unroll
    for (int t = 0; t < 2; ++t) {
        const int idx = t * 256 + tid;         // 512 groups of 8
        const int row = idx >> 3, c8 = (idx & 7) << 3;
        *(bf16x8*)&attn[(size_t)(c * CHUNK + row) * EMB + h * HD + c8] =
            *(const bf16x8*)&As[row * SP + c8];
    }
}

// ---------------------------------------------------------------------------
extern "C" void kernel_launch(void* const* d_in, const int* in_sizes, int n_in,
                              void* d_out, int out_size, void* d_ws, size_t ws_size,
                              hipStream_t stream)
{
    const float* x     = (const float*)d_in[0];
    const float* qkv_w = (const float*)d_in[1];
    const float* qkv_b = (const float*)d_in[2];
    const float* out_w = (const float*)d_in[3];
    const float* out_b = (const float*)d_in[4];
    float* out = (float*)d_out;

    short* ws    = (short*)d_ws;
    short* Qb    = ws;                   // head-major bf16, 4194304 each
    short* Kb    = Qb + 4194304;
    short* Vb    = Kb + 4194304;
    short* xb    = Vb + 4194304;
    short* qwt   = xb + 4194304;         // 3072 x 1024
    short* owt   = qwt + 3145728;        // 1024 x 1024
    short* attnb = owt + 1048576;        // 4096 x 1024
    short* S0b   = attnb + 4194304;      // 1024 * 65 * 64
    short* ScTb  = S0b + 4259840;        // 1024 * 64 * 64 (bf16)
    float* zc    = (float*)(ScTb + 4194304);   // 65536 fp32

    prep<<<dim3(3072), 256, 0, stream>>>(x, xb, qkv_w, qwt, out_w, owt);
    mfma_gemm<0><<<dim3(N3 / 128, L_SEQ / 128), 256, 0, stream>>>(
        xb, qwt, qkv_b, Qb, Kb, Vb, nullptr, N3, EMB);
    chunk_state<<<dim3(NCHUNK, NH), 256, 0, stream>>>(Kb, Vb, ScTb, zc);
    prefix_scan<<<dim3((NH * 4096) / 256), 256, 0, stream>>>(ScTb, zc, S0b);
    chunk_attn<<<dim3(NCHUNK, NH), 256, 0, stream>>>(Qb, Kb, Vb, S0b, attnb);
    mfma_gemm<1><<<dim3(EMB / 128, L_SEQ / 128), 256, 0, stream>>>(
        attnb, owt, out_b, nullptr, nullptr, nullptr, out, EMB, EMB);
}